// Round 1
// baseline (2325.653 us; speedup 1.0000x reference)
//
#include <hip/hip_runtime.h>
#include <math.h>

#ifndef __has_builtin
#define __has_builtin(x) 0
#endif

#if __has_builtin(__builtin_amdgcn_rcpf)
#define FAST_RCP(x) __builtin_amdgcn_rcpf(x)
#else
#define FAST_RCP(x) (1.0f / (x))
#endif

#if __has_builtin(__builtin_amdgcn_exp2f)
#define FAST_EXP2(x) __builtin_amdgcn_exp2f(x)
#else
#define FAST_EXP2(x) exp2f(x)
#endif

__device__ __forceinline__ float fast_sigmoid(float v) {
    // sigmoid(x) = 1 / (1 + 2^(-x*log2(e)))
    float e = FAST_EXP2(-1.44269504088896340736f * v);
    return FAST_RCP(1.0f + e);
}

__device__ __forceinline__ float fast_tanh(float v) {
    // tanh(x) = 1 - 2/(2^(2x*log2(e)) + 1); saturates gracefully via inf/0
    float e = FAST_EXP2(2.88539008177792681472f * v);
    return 1.0f - 2.0f * FAST_RCP(e + 1.0f);
}

constexpr int T_STEPS = 180;
constexpr int I_DIM = 7;

// Block = 256 threads = 4 waves, covers 4 batch elements x 64 hidden units.
// Wave w, lane l: batch_local = l>>4 (0..3), unit = w*16 + (l&15).
// Lanes sharing a unit (4 of them) read identical W_hh addresses (broadcast).
__global__ __launch_bounds__(256) void lstm_fused_kernel(
    const float* __restrict__ x,
    const float* __restrict__ W_ih,
    const float* __restrict__ W_hh,
    const float* __restrict__ b_ih,
    const float* __restrict__ b_hh,
    const float* __restrict__ W_fc,
    const float* __restrict__ b_fc,
    float* __restrict__ out) {
    __shared__ float h_sh[4][68];  // +4 pad: 4 batch rows land on distinct banks

    const int tid = (int)threadIdx.x;
    const int w   = tid >> 6;
    const int l   = tid & 63;
    const int bl  = l >> 4;                // batch element within block, 0..3
    const int u   = (w << 4) | (l & 15);   // hidden unit, 0..63
    const long batch = (long)blockIdx.x * 4 + bl;

    // Per-lane input-projection rows + fused bias in registers.
    // PyTorch gate order along 4H: i(0..63) f(64..127) g(128..191) o(192..255)
    float wih[4][I_DIM];
    float bias[4];
#pragma unroll
    for (int q = 0; q < 4; ++q) {
        const int row = q * 64 + u;
#pragma unroll
        for (int i = 0; i < I_DIM; ++i) wih[q][i] = W_ih[row * I_DIM + i];
        bias[q] = b_ih[row] + b_hh[row];
    }

    const float4* __restrict__ wr0 = (const float4*)(W_hh + (0 * 64 + u) * 64);
    const float4* __restrict__ wr1 = (const float4*)(W_hh + (1 * 64 + u) * 64);
    const float4* __restrict__ wr2 = (const float4*)(W_hh + (2 * 64 + u) * 64);
    const float4* __restrict__ wr3 = (const float4*)(W_hh + (3 * 64 + u) * 64);

    for (int i = tid; i < 4 * 68; i += 256) (&h_sh[0][0])[i] = 0.0f;
    __syncthreads();

    const float* __restrict__ xb = x + batch * (T_STEPS * I_DIM);
    float xv[I_DIM];
#pragma unroll
    for (int i = 0; i < I_DIM; ++i) xv[i] = xb[i];

    float h = 0.0f, cst = 0.0f;

    for (int t = 0; t < T_STEPS; ++t) {
        float a0 = bias[0], a1 = bias[1], a2 = bias[2], a3 = bias[3];
#pragma unroll
        for (int i = 0; i < I_DIM; ++i) {
            a0 += xv[i] * wih[0][i];
            a1 += xv[i] * wih[1][i];
            a2 += xv[i] * wih[2][i];
            a3 += xv[i] * wih[3][i];
        }
        // Prefetch next timestep's x; waitcnt lands next iteration.
        if (t + 1 < T_STEPS) {
            const float* xn = xb + (t + 1) * I_DIM;
#pragma unroll
            for (int i = 0; i < I_DIM; ++i) xv[i] = xn[i];
        }
        // Recurrent matvec: h (LDS broadcast) x W_hh rows (global, L1/L2-hot)
        const float4* hrow = (const float4*)(&h_sh[bl][0]);
#pragma unroll
        for (int k4 = 0; k4 < 16; ++k4) {
            const float4 hk = hrow[k4];
            const float4 w0 = wr0[k4];
            const float4 w1 = wr1[k4];
            const float4 w2 = wr2[k4];
            const float4 w3 = wr3[k4];
            a0 += hk.x * w0.x + hk.y * w0.y + hk.z * w0.z + hk.w * w0.w;
            a1 += hk.x * w1.x + hk.y * w1.y + hk.z * w1.z + hk.w * w1.w;
            a2 += hk.x * w2.x + hk.y * w2.y + hk.z * w2.z + hk.w * w2.w;
            a3 += hk.x * w3.x + hk.y * w3.y + hk.z * w3.z + hk.w * w3.w;
        }
        const float ig = fast_sigmoid(a0);
        const float fg = fast_sigmoid(a1);
        const float gg = fast_tanh(a2);
        const float og = fast_sigmoid(a3);
        cst = fg * cst + ig * gg;
        h   = og * fast_tanh(cst);

        __syncthreads();          // all reads of h_{t-1} complete
        h_sh[bl][u] = h;
        __syncthreads();          // h_t visible to all waves
    }

    // Epilogue: out[b][j] = b_fc[j] + sum_u h[b][u] * W_fc[j][u], wave 0 only.
    if (tid < 64) {
        const int obl = tid >> 4;
        const int j   = tid & 15;
        float s = b_fc[j];
        const float4* wf = (const float4*)(W_fc + j * 64);
        const float4* hr = (const float4*)(&h_sh[obl][0]);
#pragma unroll
        for (int k4 = 0; k4 < 16; ++k4) {
            const float4 wv = wf[k4];
            const float4 hv = hr[k4];
            s += wv.x * hv.x + wv.y * hv.y + wv.z * hv.z + wv.w * hv.w;
        }
        out[((long)blockIdx.x * 4 + obl) * 16 + j] = s;
    }
}

extern "C" void kernel_launch(void* const* d_in, const int* in_sizes, int n_in,
                              void* d_out, int out_size, void* d_ws, size_t ws_size,
                              hipStream_t stream) {
    const float* x    = (const float*)d_in[0];
    const float* W_ih = (const float*)d_in[1];
    const float* W_hh = (const float*)d_in[2];
    const float* b_ih = (const float*)d_in[3];
    const float* b_hh = (const float*)d_in[4];
    const float* W_fc = (const float*)d_in[5];
    const float* b_fc = (const float*)d_in[6];
    float* out = (float*)d_out;

    const int B = in_sizes[0] / (T_STEPS * I_DIM);  // 8192
    const int grid = B / 4;                          // 2048 blocks

    lstm_fused_kernel<<<grid, 256, 0, stream>>>(x, W_ih, W_hh, b_ih, b_hh,
                                                W_fc, b_fc, out);
}

// Round 2
// 277.865 us; speedup vs baseline: 8.3697x; 8.3697x over previous
//
#include <hip/hip_runtime.h>
#include <math.h>

#ifndef __has_builtin
#define __has_builtin(x) 0
#endif

#if __has_builtin(__builtin_amdgcn_rcpf)
#define FAST_RCP(x) __builtin_amdgcn_rcpf(x)
#else
#define FAST_RCP(x) (1.0f / (x))
#endif

#if __has_builtin(__builtin_amdgcn_exp2f)
#define FAST_EXP2(x) __builtin_amdgcn_exp2f(x)
#else
#define FAST_EXP2(x) exp2f(x)
#endif

__device__ __forceinline__ float fast_sigmoid(float v) {
    float e = FAST_EXP2(-1.44269504088896340736f * v);
    return FAST_RCP(1.0f + e);
}

__device__ __forceinline__ float fast_tanh(float v) {
    float e = FAST_EXP2(2.88539008177792681472f * v);
    return 1.0f - 2.0f * FAST_RCP(e + 1.0f);
}

typedef _Float16 half8 __attribute__((ext_vector_type(8)));
typedef float f32x4 __attribute__((ext_vector_type(4)));

constexpr int T_STEPS = 180;
constexpr int I_DIM   = 7;
constexpr int HDIM    = 64;
constexpr int BT      = 16;   // batch tile per block
constexpr int KAUG    = 96;   // 7 x + 1 bias + 64 h + 24 pad (3 K=32 chunks)
constexpr int GROWS   = 256;  // 4 gates * 64 units
constexpr int GSTRIDE = 17;   // gates LDS row stride (dwords), +1 style pad

// Block = 512 threads = 8 waves. Wave w owns gate-row tiles {2w, 2w+1}.
// GEMM per step: gates[256 x 16] = W_aug[256 x 96(f16)] . v[96 x 16(f16)]
// A (weights) stays in registers for all 180 steps.
__global__ __launch_bounds__(512) void lstm_mfma_kernel(
    const float* __restrict__ x,
    const float* __restrict__ W_ih,
    const float* __restrict__ W_hh,
    const float* __restrict__ b_ih,
    const float* __restrict__ b_hh,
    const float* __restrict__ W_fc,
    const float* __restrict__ b_fc,
    float* __restrict__ out) {
    __shared__ alignas(16) _Float16 Blds[BT][KAUG];   // v^T: [n][k], row 192B
    __shared__ float glds[GROWS * GSTRIDE];           // gates fp32, padded

    const int tid  = (int)threadIdx.x;
    const int w    = tid >> 6;
    const int lane = tid & 63;
    const int q    = lane >> 4;   // quad 0..3
    const int n15  = lane & 15;   // batch col within tile
    const long bbase = (long)blockIdx.x * BT;

    // ---- A fragments: A[m][k], m = rt*16 + n15, k = kc*32 + q*8 + j ----
    half8 afrag[2][3];
#pragma unroll
    for (int pt = 0; pt < 2; ++pt) {
        const int m = (2 * w + pt) * 16 + n15;
#pragma unroll
        for (int kc = 0; kc < 3; ++kc) {
#pragma unroll
            for (int j = 0; j < 8; ++j) {
                const int k = kc * 32 + q * 8 + j;
                float v;
                if (k < I_DIM)            v = W_ih[m * I_DIM + k];
                else if (k == I_DIM)      v = b_ih[m] + b_hh[m];
                else if (k < 8 + HDIM)    v = W_hh[m * HDIM + (k - 8)];
                else                      v = 0.0f;
                afrag[pt][kc][j] = (_Float16)v;
            }
        }
    }

    // ---- init v_0 = [x_0, 1, h=0, pad=0] ----
    for (int idx = tid; idx < BT * KAUG; idx += 512) {
        const int n = idx / KAUG, k = idx % KAUG;
        float v = 0.0f;
        if (k < I_DIM)       v = x[(bbase + n) * (T_STEPS * I_DIM) + k];
        else if (k == I_DIM) v = 1.0f;
        Blds[n][k] = (_Float16)v;
    }
    __syncthreads();

    // cell-state ownership: thread -> (u, b) pairs
    const int ucell = tid >> 4;   // 0..31
    const int bcell = tid & 15;
    float c0 = 0.0f, c1 = 0.0f;

    // x prefetch lanes: threads 0..127, (n = tid>>3, i = tid&7), i<7 active
    const int xn = tid >> 3, xi = tid & 7;
    const bool xact = (tid < 128) && (xi < I_DIM);
    const float* xrow = x + (bbase + xn) * (T_STEPS * I_DIM);

    for (int t = 0; t < T_STEPS; ++t) {
        float xpre = 0.0f;
        const bool xnow = xact && (t + 1 < T_STEPS);
        if (xnow) xpre = xrow[(t + 1) * I_DIM + xi];

        // B fragments: B[k][n] from Blds[n][k], one b128 per chunk
        half8 bfrag[3];
#pragma unroll
        for (int kc = 0; kc < 3; ++kc)
            bfrag[kc] = *(const half8*)&Blds[n15][kc * 32 + q * 8];

        f32x4 acc0 = {0.f, 0.f, 0.f, 0.f};
        f32x4 acc1 = {0.f, 0.f, 0.f, 0.f};
#pragma unroll
        for (int kc = 0; kc < 3; ++kc) {
            acc0 = __builtin_amdgcn_mfma_f32_16x16x32_f16(afrag[0][kc], bfrag[kc], acc0, 0, 0, 0);
            acc1 = __builtin_amdgcn_mfma_f32_16x16x32_f16(afrag[1][kc], bfrag[kc], acc1, 0, 0, 0);
        }

        // scatter gates to LDS: D[row=tilebase+q*4+reg][col=n15]
        {
            const int r0 = (2 * w + 0) * 16 + q * 4;
            const int r1 = (2 * w + 1) * 16 + q * 4;
#pragma unroll
            for (int reg = 0; reg < 4; ++reg) {
                glds[(r0 + reg) * GSTRIDE + n15] = acc0[reg];
                glds[(r1 + reg) * GSTRIDE + n15] = acc1[reg];
            }
        }
        __syncthreads();   // gates visible; B_lds reads of this step complete

        // cell update: 2 (u,b) pairs per thread
#pragma unroll
        for (int p = 0; p < 2; ++p) {
            const int u = ucell + 32 * p;
            const float ig = glds[(0 * 64 + u) * GSTRIDE + bcell];
            const float fg = glds[(1 * 64 + u) * GSTRIDE + bcell];
            const float gg = glds[(2 * 64 + u) * GSTRIDE + bcell];
            const float og = glds[(3 * 64 + u) * GSTRIDE + bcell];
            const float iv = fast_sigmoid(ig);
            const float fv = fast_sigmoid(fg);
            const float gv = fast_tanh(gg);
            const float ov = fast_sigmoid(og);
            float& c = p ? c1 : c0;
            c = fv * c + iv * gv;
            const float h = ov * fast_tanh(c);
            Blds[bcell][8 + u] = (_Float16)h;
            if (t == T_STEPS - 1) glds[u * GSTRIDE + bcell] = h;  // fp32 h for epilogue
        }
        if (xnow) Blds[xn][xi] = (_Float16)xpre;
        __syncthreads();   // v_{t+1} ready
    }

    // epilogue: out[b][j] = b_fc[j] + sum_u h[b][u] * W_fc[j][u]
    if (tid < 256) {
        const int b = tid >> 4, j = tid & 15;
        float s = b_fc[j];
#pragma unroll 8
        for (int u = 0; u < HDIM; ++u)
            s += glds[u * GSTRIDE + b] * W_fc[j * HDIM + u];
        out[(bbase + b) * 16 + j] = s;
    }
}

extern "C" void kernel_launch(void* const* d_in, const int* in_sizes, int n_in,
                              void* d_out, int out_size, void* d_ws, size_t ws_size,
                              hipStream_t stream) {
    const float* x    = (const float*)d_in[0];
    const float* W_ih = (const float*)d_in[1];
    const float* W_hh = (const float*)d_in[2];
    const float* b_ih = (const float*)d_in[3];
    const float* b_hh = (const float*)d_in[4];
    const float* W_fc = (const float*)d_in[5];
    const float* b_fc = (const float*)d_in[6];
    float* out = (float*)d_out;

    const int B = in_sizes[0] / (T_STEPS * I_DIM);  // 8192
    const int grid = B / BT;                         // 512 blocks

    lstm_mfma_kernel<<<grid, 512, 0, stream>>>(x, W_ih, W_hh, b_ih, b_hh,
                                               W_fc, b_fc, out);
}

// Round 3
// 230.610 us; speedup vs baseline: 10.0848x; 1.2049x over previous
//
#include <hip/hip_runtime.h>
#include <math.h>

#ifndef __has_builtin
#define __has_builtin(x) 0
#endif

#if __has_builtin(__builtin_amdgcn_rcpf)
#define FAST_RCP(x) __builtin_amdgcn_rcpf(x)
#else
#define FAST_RCP(x) (1.0f / (x))
#endif

#if __has_builtin(__builtin_amdgcn_exp2f)
#define FAST_EXP2(x) __builtin_amdgcn_exp2f(x)
#else
#define FAST_EXP2(x) exp2f(x)
#endif

__device__ __forceinline__ float fast_sigmoid(float v) {
    float e = FAST_EXP2(-1.44269504088896340736f * v);
    return FAST_RCP(1.0f + e);
}

__device__ __forceinline__ float fast_tanh(float v) {
    float e = FAST_EXP2(2.88539008177792681472f * v);
    return 1.0f - 2.0f * FAST_RCP(e + 1.0f);
}

typedef _Float16 half8 __attribute__((ext_vector_type(8)));
typedef float f32x4 __attribute__((ext_vector_type(4)));

constexpr int T_STEPS  = 180;
constexpr int I_DIM    = 7;
constexpr int HDIM     = 64;
constexpr int BT       = 16;    // batch tile per block
constexpr int BSTRIDE  = 104;   // halfs per B row (96 data + 8 pad; 52 dw, bank-friendly)

// Block = 512 threads = 8 waves, 16 batch columns, 180 steps.
// Per step GEMM: gates[256 x 16] = W_aug[256 x 96(f16)] . v[96 x 16(f16)]
//   v = [x_t(7), 1, h_{t-1}(64), pad(24)]
// A rows packed UNIT-MAJOR: row r -> unit 4*(r>>4)+((r&15)>>2), gate r&3.
// => lane (q,n15), tile rt: acc regs = gates i,f,g,o of unit 4*rt+q, batch n15.
// Cell update is pure register math; only h (2 b16) returns to LDS per step.
// Double-buffered B => ONE barrier per step.
__global__ __launch_bounds__(512) void lstm_mfma_kernel(
    const float* __restrict__ x,
    const float* __restrict__ W_ih,
    const float* __restrict__ W_hh,
    const float* __restrict__ b_ih,
    const float* __restrict__ b_hh,
    const float* __restrict__ W_fc,
    const float* __restrict__ b_fc,
    float* __restrict__ out) {
    __shared__ alignas(16) _Float16 Blds[2][BT][BSTRIDE];
    __shared__ float hlds[BT][HDIM + 4];   // fp32 h_T for epilogue

    const int tid  = (int)threadIdx.x;
    const int w    = tid >> 6;
    const int lane = tid & 63;
    const int q    = lane >> 4;   // quad 0..3
    const int n15  = lane & 15;   // batch col within tile
    const long bbase = (long)blockIdx.x * BT;

    // ---- A fragments (held in registers for all 180 steps) ----
    // A[m=n15][k=q*8+j] per 16x16 tile; global row r=(2w+pt)*16+n15.
    half8 afrag[2][3];
#pragma unroll
    for (int pt = 0; pt < 2; ++pt) {
        const int rt   = 2 * w + pt;
        const int unit = 4 * rt + (n15 >> 2);
        const int gate = n15 & 3;
        const int grow = gate * HDIM + unit;   // row in PyTorch [4H, *] params
#pragma unroll
        for (int kc = 0; kc < 3; ++kc) {
#pragma unroll
            for (int j = 0; j < 8; ++j) {
                const int k = kc * 32 + q * 8 + j;
                float v;
                if (k < I_DIM)            v = W_ih[grow * I_DIM + k];
                else if (k == I_DIM)      v = b_ih[grow] + b_hh[grow];
                else if (k < 8 + HDIM)    v = W_hh[grow * HDIM + (k - 8)];
                else                      v = 0.0f;
                afrag[pt][kc][j] = (_Float16)v;
            }
        }
    }

    // ---- init both B buffers: bias col = 1, h = 0, pad = 0; buf0 x = x_0 ----
    for (int idx = tid; idx < 2 * BT * BSTRIDE; idx += 512) {
        const int buf = idx / (BT * BSTRIDE);
        const int rem = idx % (BT * BSTRIDE);
        const int n = rem / BSTRIDE, k = rem % BSTRIDE;
        float v = 0.0f;
        if (k == I_DIM)                 v = 1.0f;
        else if (k < I_DIM && buf == 0) v = x[(bbase + n) * (T_STEPS * I_DIM) + k];
        Blds[buf][n][k] = (_Float16)v;
    }
    __syncthreads();

    // cell ownership: lane (w,q,n15) owns units u0=8w+q, u1=8w+4+q, batch n15
    const int u0 = 8 * w + q;
    const int u1 = u0 + 4;

    // x prefetch lanes: threads 0..127, (n = tid>>3, i = tid&7), i<7 active
    const int xn = tid >> 3, xi = tid & 7;
    const bool xact = (tid < 128) && (xi < I_DIM);
    const float* xrow = x + (bbase + xn) * (T_STEPS * I_DIM);

    float c0 = 0.0f, c1 = 0.0f, h0 = 0.0f, h1 = 0.0f;

    for (int t = 0; t < T_STEPS; ++t) {
        const int cur = t & 1, nxt = cur ^ 1;

        float xpre = 0.0f;
        const bool xnow = xact && (t + 1 < T_STEPS);
        if (xnow) xpre = xrow[(t + 1) * I_DIM + xi];

        const _Float16* rb = &Blds[cur][n15][q * 8];
        const half8 bf0 = *(const half8*)(rb);
        const half8 bf1 = *(const half8*)(rb + 32);
        const half8 bf2 = *(const half8*)(rb + 64);

        f32x4 acc0 = {0.f, 0.f, 0.f, 0.f};
        f32x4 acc1 = {0.f, 0.f, 0.f, 0.f};
        acc0 = __builtin_amdgcn_mfma_f32_16x16x32_f16(afrag[0][0], bf0, acc0, 0, 0, 0);
        acc1 = __builtin_amdgcn_mfma_f32_16x16x32_f16(afrag[1][0], bf0, acc1, 0, 0, 0);
        acc0 = __builtin_amdgcn_mfma_f32_16x16x32_f16(afrag[0][1], bf1, acc0, 0, 0, 0);
        acc1 = __builtin_amdgcn_mfma_f32_16x16x32_f16(afrag[1][1], bf1, acc1, 0, 0, 0);
        acc0 = __builtin_amdgcn_mfma_f32_16x16x32_f16(afrag[0][2], bf2, acc0, 0, 0, 0);
        acc1 = __builtin_amdgcn_mfma_f32_16x16x32_f16(afrag[1][2], bf2, acc1, 0, 0, 0);

        // cell update, all in registers (acc regs = i,f,g,o of the owned unit)
        {
            const float iv = fast_sigmoid(acc0[0]);
            const float fv = fast_sigmoid(acc0[1]);
            const float gv = fast_tanh(acc0[2]);
            const float ov = fast_sigmoid(acc0[3]);
            c0 = fv * c0 + iv * gv;
            h0 = ov * fast_tanh(c0);
        }
        {
            const float iv = fast_sigmoid(acc1[0]);
            const float fv = fast_sigmoid(acc1[1]);
            const float gv = fast_tanh(acc1[2]);
            const float ov = fast_sigmoid(acc1[3]);
            c1 = fv * c1 + iv * gv;
            h1 = ov * fast_tanh(c1);
        }

        Blds[nxt][n15][8 + u0] = (_Float16)h0;
        Blds[nxt][n15][8 + u1] = (_Float16)h1;
        if (xnow) Blds[nxt][xn][xi] = (_Float16)xpre;

        __syncthreads();   // v_{t+1} complete; old buffer free for rewrite
    }

    // ---- epilogue: out[b][j] = b_fc[j] + sum_u h[b][u] * W_fc[j][u] ----
    hlds[n15][u0] = h0;
    hlds[n15][u1] = h1;
    __syncthreads();
    if (tid < 256) {
        const int b = tid >> 4, j = tid & 15;
        float s = b_fc[j];
#pragma unroll 8
        for (int u = 0; u < HDIM; ++u)
            s += hlds[b][u] * W_fc[j * HDIM + u];
        out[(bbase + b) * 16 + j] = s;
    }
}

extern "C" void kernel_launch(void* const* d_in, const int* in_sizes, int n_in,
                              void* d_out, int out_size, void* d_ws, size_t ws_size,
                              hipStream_t stream) {
    const float* x    = (const float*)d_in[0];
    const float* W_ih = (const float*)d_in[1];
    const float* W_hh = (const float*)d_in[2];
    const float* b_ih = (const float*)d_in[3];
    const float* b_hh = (const float*)d_in[4];
    const float* W_fc = (const float*)d_in[5];
    const float* b_fc = (const float*)d_in[6];
    float* out = (float*)d_out;

    const int B = in_sizes[0] / (T_STEPS * I_DIM);  // 8192
    const int grid = B / BT;                         // 512 blocks

    lstm_mfma_kernel<<<grid, 512, 0, stream>>>(x, W_ih, W_hh, b_ih, b_hh,
                                               W_fc, b_fc, out);
}

// Round 4
// 227.979 us; speedup vs baseline: 10.2012x; 1.0115x over previous
//
#include <hip/hip_runtime.h>
#include <math.h>

#ifndef __has_builtin
#define __has_builtin(x) 0
#endif

#if __has_builtin(__builtin_amdgcn_rcpf)
#define FAST_RCP(x) __builtin_amdgcn_rcpf(x)
#else
#define FAST_RCP(x) (1.0f / (x))
#endif

#if __has_builtin(__builtin_amdgcn_exp2f)
#define FAST_EXP2(x) __builtin_amdgcn_exp2f(x)
#else
#define FAST_EXP2(x) exp2f(x)
#endif

typedef _Float16 half8 __attribute__((ext_vector_type(8)));
typedef float f32x4 __attribute__((ext_vector_type(4)));

constexpr int T_STEPS  = 180;
constexpr int I_DIM    = 7;
constexpr int HDIM     = 64;
constexpr int BT       = 16;    // batch tile per block
constexpr int BSTRIDE  = 104;   // halfs per B row (96 data + 8 pad; 52 dw)

// Block = 1024 threads = 16 waves; wave w owns row-tile w (16 of 256 gate rows).
// Per step GEMM: gates[256 x 16] = W_aug[256 x 96(f16)] . v[96 x 16(f16)]
//   v = [x_t(7), 1, h_{t-1}(64), pad(24)]
// A rows packed UNIT-MAJOR (row r -> unit 4*(r>>4)+((r&15)>>2), gate r&3) so
// each lane's 4 acc regs = gates i,f,g,o of ONE (unit,batch) cell.
// Activation-scale constants are pre-folded into the weights:
//   gates i,f,o rows are scaled by -log2(e); gate g rows by +2*log2(e),
// so MFMA outputs feed exp2 directly:
//   sigma(a) = rcp(1 + exp2(a')),  tanh(b) = (E-1)/(E+1), E = exp2(b')
//   sigma(a)*tanh(b) = (E-1) * rcp((1+A)*(E+1))   <- ONE rcp for the pair.
// => 8 transcendentals/cell (5 exp2 + 3 rcp) instead of 10.
__global__ __launch_bounds__(1024, 8) void lstm_mfma_kernel(
    const float* __restrict__ x,
    const float* __restrict__ W_ih,
    const float* __restrict__ W_hh,
    const float* __restrict__ b_ih,
    const float* __restrict__ b_hh,
    const float* __restrict__ W_fc,
    const float* __restrict__ b_fc,
    float* __restrict__ out) {
    __shared__ alignas(16) _Float16 Blds[2][BT][BSTRIDE];
    __shared__ float hlds[BT][HDIM + 4];   // fp32 h_T for epilogue

    const int tid  = (int)threadIdx.x;
    const int w    = tid >> 6;    // wave 0..15 = row-tile
    const int lane = tid & 63;
    const int q    = lane >> 4;   // quad 0..3
    const int n15  = lane & 15;   // batch col within tile
    const long bbase = (long)blockIdx.x * BT;

    // ---- A fragments, scale-folded, held in registers for all 180 steps ----
    // A[m=n15][k=q*8+j]; packed row p = w*16+n15 -> unit 4w+(n15>>2), gate n15&3
    half8 afrag[3];
    {
        const int unit = 4 * w + (n15 >> 2);
        const int gate = n15 & 3;
        const int grow = gate * HDIM + unit;   // row in PyTorch [4H, *] params
        const float scl = (gate == 2) ? 2.88539008177792681472f
                                      : -1.44269504088896340736f;
#pragma unroll
        for (int kc = 0; kc < 3; ++kc) {
#pragma unroll
            for (int j = 0; j < 8; ++j) {
                const int k = kc * 32 + q * 8 + j;
                float v;
                if (k < I_DIM)            v = W_ih[grow * I_DIM + k];
                else if (k == I_DIM)      v = b_ih[grow] + b_hh[grow];
                else if (k < 8 + HDIM)    v = W_hh[grow * HDIM + (k - 8)];
                else                      v = 0.0f;
                afrag[kc][j] = (_Float16)(scl * v);
            }
        }
    }

    // ---- init both B buffers: bias col = 1, h = 0, pad = 0; buf0 x = x_0 ----
    for (int idx = tid; idx < 2 * BT * BSTRIDE; idx += 1024) {
        const int buf = idx / (BT * BSTRIDE);
        const int rem = idx % (BT * BSTRIDE);
        const int n = rem / BSTRIDE, k = rem % BSTRIDE;
        float v = 0.0f;
        if (k == I_DIM)                 v = 1.0f;
        else if (k < I_DIM && buf == 0) v = x[(bbase + n) * (T_STEPS * I_DIM) + k];
        Blds[buf][n][k] = (_Float16)v;
    }
    __syncthreads();

    // cell ownership: lane (w,q,n15) owns unit u = 4w+q, batch n15
    const int ucell = 4 * w + q;

    // x prefetch lanes: threads 0..127, (n = tid>>3, i = tid&7), i<7 active
    const int xn = tid >> 3, xi = tid & 7;
    const bool xact = (tid < 128) && (xi < I_DIM);
    const float* xrow = x + (bbase + xn) * (T_STEPS * I_DIM);

    float c = 0.0f, h = 0.0f;

    for (int t = 0; t < T_STEPS; ++t) {
        const int cur = t & 1, nxt = cur ^ 1;

        float xpre = 0.0f;
        const bool xnow = xact && (t + 1 < T_STEPS);
        if (xnow) xpre = xrow[(t + 1) * I_DIM + xi];

        const _Float16* rb = &Blds[cur][n15][q * 8];
        const half8 bf0 = *(const half8*)(rb);
        const half8 bf1 = *(const half8*)(rb + 32);
        const half8 bf2 = *(const half8*)(rb + 64);

        f32x4 acc = {0.f, 0.f, 0.f, 0.f};
        acc = __builtin_amdgcn_mfma_f32_16x16x32_f16(afrag[0], bf0, acc, 0, 0, 0);
        acc = __builtin_amdgcn_mfma_f32_16x16x32_f16(afrag[1], bf1, acc, 0, 0, 0);
        acc = __builtin_amdgcn_mfma_f32_16x16x32_f16(afrag[2], bf2, acc, 0, 0, 0);

        // cell update in registers. acc = {i', f', g', o'} pre-scaled.
        {
            const float A = FAST_EXP2(acc[0]);          // exp2(-log2e * a_i)
            const float F = FAST_EXP2(acc[1]);
            const float E = FAST_EXP2(acc[2]);          // exp2(2 log2e * a_g)
            const float O = FAST_EXP2(acc[3]);
            const float ig = (E - 1.0f) * FAST_RCP((1.0f + A) * (E + 1.0f));
            const float fv = FAST_RCP(1.0f + F);
            c = fv * c + ig;
            float cs = 2.88539008177792681472f * c;
            cs = fminf(fmaxf(cs, -80.0f), 80.0f);       // keep exp2 finite
            const float C = FAST_EXP2(cs);
            h = (C - 1.0f) * FAST_RCP((1.0f + O) * (C + 1.0f));
        }

        Blds[nxt][n15][8 + ucell] = (_Float16)h;
        if (xnow) Blds[nxt][xn][xi] = (_Float16)xpre;

        __syncthreads();   // v_{t+1} complete; old buffer free for rewrite
    }

    // ---- epilogue: out[b][j] = b_fc[j] + sum_u h[b][u] * W_fc[j][u] ----
    hlds[n15][ucell] = h;
    __syncthreads();
    if (tid < 256) {
        const int b = tid >> 4, j = tid & 15;
        float s = b_fc[j];
#pragma unroll 8
        for (int u = 0; u < HDIM; ++u)
            s += hlds[b][u] * W_fc[j * HDIM + u];
        out[(bbase + b) * 16 + j] = s;
    }
}

extern "C" void kernel_launch(void* const* d_in, const int* in_sizes, int n_in,
                              void* d_out, int out_size, void* d_ws, size_t ws_size,
                              hipStream_t stream) {
    const float* x    = (const float*)d_in[0];
    const float* W_ih = (const float*)d_in[1];
    const float* W_hh = (const float*)d_in[2];
    const float* b_ih = (const float*)d_in[3];
    const float* b_hh = (const float*)d_in[4];
    const float* W_fc = (const float*)d_in[5];
    const float* b_fc = (const float*)d_in[6];
    float* out = (float*)d_out;

    const int B = in_sizes[0] / (T_STEPS * I_DIM);  // 8192
    const int grid = B / BT;                         // 512 blocks

    lstm_mfma_kernel<<<grid, 1024, 0, stream>>>(x, W_ih, W_hh, b_ih, b_hh,
                                                W_fc, b_fc, out);
}

// Round 5
// 204.293 us; speedup vs baseline: 11.3839x; 1.1159x over previous
//
#include <hip/hip_runtime.h>
#include <math.h>

#ifndef __has_builtin
#define __has_builtin(x) 0
#endif

#if __has_builtin(__builtin_amdgcn_rcpf)
#define FAST_RCP(x) __builtin_amdgcn_rcpf(x)
#else
#define FAST_RCP(x) (1.0f / (x))
#endif

#if __has_builtin(__builtin_amdgcn_exp2f)
#define FAST_EXP2(x) __builtin_amdgcn_exp2f(x)
#else
#define FAST_EXP2(x) exp2f(x)
#endif

typedef _Float16 half8 __attribute__((ext_vector_type(8)));
typedef float f32x4 __attribute__((ext_vector_type(4)));

constexpr int T_STEPS  = 180;
constexpr int I_DIM    = 7;
constexpr int HDIM     = 64;
constexpr int BT       = 16;    // batch tile per block
constexpr int BSTRIDE  = 104;   // halfs per B row: 208 B, 16B-aligned rows

// Block = 1024 threads = 16 waves; wave w owns row-tile w (16 of 256 gate rows).
// Per step GEMM: gates[256 x 16] = W_aug[256 x 96(f16)] . v[96 x 16(f16)]
//   v = [x_t(7), 1, h_{t-1}(64), pad(24)]
// A rows packed UNIT-MAJOR so each lane's 4 acc regs = i,f,g,o of ONE cell;
// activation scales pre-folded into weights (exp2-ready gate pre-activations).
// x prefetch is a 2-STEP-DEEP register pipeline: the global load issued at
// step t is consumed (written to LDS) at step t+2, so HBM latency (~900 cyc)
// never sits on the per-step barrier. One barrier per step, double-buffered B.
__global__ __launch_bounds__(1024, 8) void lstm_mfma_kernel(
    const float* __restrict__ x,
    const float* __restrict__ W_ih,
    const float* __restrict__ W_hh,
    const float* __restrict__ b_ih,
    const float* __restrict__ b_hh,
    const float* __restrict__ W_fc,
    const float* __restrict__ b_fc,
    float* __restrict__ out) {
    __shared__ alignas(16) _Float16 Blds[2][BT][BSTRIDE];
    __shared__ float hlds[BT][HDIM + 4];   // fp32 h_T for epilogue

    const int tid  = (int)threadIdx.x;
    const int w    = tid >> 6;    // wave 0..15 = row-tile
    const int lane = tid & 63;
    const int q    = lane >> 4;   // quad 0..3
    const int n15  = lane & 15;   // batch col within tile
    const long bbase = (long)blockIdx.x * BT;

    // ---- A fragments, scale-folded, in registers for all 180 steps ----
    half8 afrag[3];
    {
        const int unit = 4 * w + (n15 >> 2);
        const int gate = n15 & 3;
        const int grow = gate * HDIM + unit;   // row in PyTorch [4H, *] params
        const float scl = (gate == 2) ? 2.88539008177792681472f
                                      : -1.44269504088896340736f;
#pragma unroll
        for (int kc = 0; kc < 3; ++kc) {
#pragma unroll
            for (int j = 0; j < 8; ++j) {
                const int k = kc * 32 + q * 8 + j;
                float v;
                if (k < I_DIM)            v = W_ih[grow * I_DIM + k];
                else if (k == I_DIM)      v = b_ih[grow] + b_hh[grow];
                else if (k < 8 + HDIM)    v = W_hh[grow * HDIM + (k - 8)];
                else                      v = 0.0f;
                afrag[kc][j] = (_Float16)(scl * v);
            }
        }
    }

    // ---- init both B buffers: bias col = 1, h = 0, pad = 0; buf0 x = x_0 ----
    for (int idx = tid; idx < 2 * BT * BSTRIDE; idx += 1024) {
        const int buf = idx / (BT * BSTRIDE);
        const int rem = idx % (BT * BSTRIDE);
        const int n = rem / BSTRIDE, k = rem % BSTRIDE;
        float v = 0.0f;
        if (k == I_DIM)                 v = 1.0f;
        else if (k < I_DIM && buf == 0) v = x[(bbase + n) * (T_STEPS * I_DIM) + k];
        Blds[buf][n][k] = (_Float16)v;
    }
    __syncthreads();

    // cell ownership: lane (w,q,n15) owns unit u = 4w+q, batch n15
    const int ucell = 4 * w + q;

    // hoisted LDS pointers (all loop-invariant)
    const _Float16* const rb0 = &Blds[0][n15][q * 8];
    const _Float16* const rb1 = &Blds[1][n15][q * 8];
    _Float16* const hw0 = &Blds[0][n15][8 + ucell];
    _Float16* const hw1 = &Blds[1][n15][8 + ucell];

    // x prefetch lanes: threads 0..127, (n = tid>>3, i = tid&7), i<7 active
    const int xn = tid >> 3, xi = tid & 7;
    const bool xact = (tid < 128) && (xi < I_DIM);
    const float* const xcol = x + (bbase + xn) * (T_STEPS * I_DIM) + xi;
    _Float16* const xw0 = &Blds[0][xn][xi];
    _Float16* const xw1 = &Blds[1][xn][xi];

    // 2-deep x pipeline: xA holds x_{t+1} at even t, xB at odd t
    float xA = xact ? xcol[1 * I_DIM] : 0.0f;   // x_1 (written during t=0)
    float xB = xact ? xcol[2 * I_DIM] : 0.0f;   // x_2 (written during t=1)

    float c = 0.0f, h = 0.0f;

#define LSTM_STEP(TT, RB, HW, XW, XREG)                                        \
    {                                                                          \
        const half8 bf0 = *(const half8*)(RB);                                 \
        const half8 bf1 = *(const half8*)((RB) + 32);                          \
        const half8 bf2 = *(const half8*)((RB) + 64);                          \
        if (xact && ((TT) + 1 < T_STEPS)) *(XW) = (_Float16)XREG;              \
        {                                                                      \
            int tl = (TT) + 3;                                                 \
            if (tl >= T_STEPS) tl = T_STEPS - 1;                               \
            if (xact) XREG = xcol[tl * I_DIM];                                 \
        }                                                                      \
        f32x4 acc = {0.f, 0.f, 0.f, 0.f};                                      \
        acc = __builtin_amdgcn_mfma_f32_16x16x32_f16(afrag[0], bf0, acc, 0, 0, 0); \
        acc = __builtin_amdgcn_mfma_f32_16x16x32_f16(afrag[1], bf1, acc, 0, 0, 0); \
        acc = __builtin_amdgcn_mfma_f32_16x16x32_f16(afrag[2], bf2, acc, 0, 0, 0); \
        const float A = FAST_EXP2(acc[0]);                                     \
        const float F = FAST_EXP2(acc[1]);                                     \
        const float E = FAST_EXP2(acc[2]);                                     \
        const float O = FAST_EXP2(acc[3]);                                     \
        const float ig = (E - 1.0f) * FAST_RCP((1.0f + A) * (E + 1.0f));       \
        const float fv = FAST_RCP(1.0f + F);                                   \
        c = fv * c + ig;                                                       \
        float cs = 2.88539008177792681472f * c;                                \
        cs = fminf(fmaxf(cs, -80.0f), 80.0f);                                  \
        const float C = FAST_EXP2(cs);                                         \
        h = (C - 1.0f) * FAST_RCP((1.0f + O) * (C + 1.0f));                    \
        *(HW) = (_Float16)h;                                                   \
        __syncthreads();                                                       \
    }

    for (int t = 0; t < T_STEPS; t += 2) {
        // even step: read buf0, write buf1, x pipeline reg A
        LSTM_STEP(t, rb0, hw1, xw1, xA)
        // odd step: read buf1, write buf0, x pipeline reg B
        LSTM_STEP(t + 1, rb1, hw0, xw0, xB)
    }
#undef LSTM_STEP

    // ---- epilogue: out[b][j] = b_fc[j] + sum_u h[b][u] * W_fc[j][u] ----
    hlds[n15][ucell] = h;
    __syncthreads();
    if (tid < 256) {
        const int b = tid >> 4, j = tid & 15;
        float s = b_fc[j];
#pragma unroll 8
        for (int u = 0; u < HDIM; ++u)
            s += hlds[b][u] * W_fc[j * HDIM + u];
        out[(bbase + b) * 16 + j] = s;
    }
}

extern "C" void kernel_launch(void* const* d_in, const int* in_sizes, int n_in,
                              void* d_out, int out_size, void* d_ws, size_t ws_size,
                              hipStream_t stream) {
    const float* x    = (const float*)d_in[0];
    const float* W_ih = (const float*)d_in[1];
    const float* W_hh = (const float*)d_in[2];
    const float* b_ih = (const float*)d_in[3];
    const float* b_hh = (const float*)d_in[4];
    const float* W_fc = (const float*)d_in[5];
    const float* b_fc = (const float*)d_in[6];
    float* out = (float*)d_out;

    const int B = in_sizes[0] / (T_STEPS * I_DIM);  // 8192
    const int grid = B / BT;                         // 512 blocks

    lstm_mfma_kernel<<<grid, 1024, 0, stream>>>(x, W_ih, W_hh, b_ih, b_hh,
                                                W_fc, b_fc, out);
}

// Round 6
// 201.247 us; speedup vs baseline: 11.5562x; 1.0151x over previous
//
#include <hip/hip_runtime.h>
#include <math.h>

#ifndef __has_builtin
#define __has_builtin(x) 0
#endif

#if __has_builtin(__builtin_amdgcn_rcpf)
#define FAST_RCP(x) __builtin_amdgcn_rcpf(x)
#else
#define FAST_RCP(x) (1.0f / (x))
#endif

#if __has_builtin(__builtin_amdgcn_exp2f)
#define FAST_EXP2(x) __builtin_amdgcn_exp2f(x)
#else
#define FAST_EXP2(x) exp2f(x)
#endif

typedef _Float16 half8 __attribute__((ext_vector_type(8)));
typedef float f32x4 __attribute__((ext_vector_type(4)));

constexpr int T_STEPS  = 180;
constexpr int I_DIM    = 7;
constexpr int HDIM     = 64;
constexpr int BT       = 16;    // batch tile per block
constexpr int BSTRIDE  = 104;   // halfs per B row: 208 B, 16B-aligned rows

// Block = 512 threads = 8 waves; wave w owns row-tiles {2w, 2w+1} (32 of 256
// gate rows) -> ONE set of B-fragment reads (3 x b128) feeds 6 MFMAs and 2
// cells/thread. This halves DS-pipe traffic per batch vs 1-cell/thread.
// Per step GEMM: gates[256 x 16] = W_aug[256 x 96(f16)] . v[96 x 16(f16)]
//   v = [x_t(7), 1, h_{t-1}(64), pad(24)]
// A rows packed UNIT-MAJOR so each lane's 4 acc regs = i,f,g,o of ONE cell;
// activation scales pre-folded into weights (exp2-ready pre-activations).
// 2-step-deep x register pipeline; one barrier per step; double-buffered B.
__global__ __launch_bounds__(512, 4) void lstm_mfma_kernel(
    const float* __restrict__ x,
    const float* __restrict__ W_ih,
    const float* __restrict__ W_hh,
    const float* __restrict__ b_ih,
    const float* __restrict__ b_hh,
    const float* __restrict__ W_fc,
    const float* __restrict__ b_fc,
    float* __restrict__ out) {
    __shared__ alignas(16) _Float16 Blds[2][BT][BSTRIDE];
    __shared__ float hlds[BT][HDIM + 4];   // fp32 h_T for epilogue

    const int tid  = (int)threadIdx.x;
    const int w    = tid >> 6;    // wave 0..7
    const int lane = tid & 63;
    const int q    = lane >> 4;   // quad 0..3
    const int n15  = lane & 15;   // batch col within tile
    const long bbase = (long)blockIdx.x * BT;

    // ---- A fragments, scale-folded, in registers for all 180 steps ----
    // tile rt=(2w+pt): A[m=n15][k=q*8+j]; packed row -> unit 4*rt+(n15>>2),
    // gate n15&3; param row grow = gate*64 + unit.
    half8 afrag[2][3];
#pragma unroll
    for (int pt = 0; pt < 2; ++pt) {
        const int rt   = 2 * w + pt;
        const int unit = 4 * rt + (n15 >> 2);
        const int gate = n15 & 3;
        const int grow = gate * HDIM + unit;
        const float scl = (gate == 2) ? 2.88539008177792681472f
                                      : -1.44269504088896340736f;
#pragma unroll
        for (int kc = 0; kc < 3; ++kc) {
#pragma unroll
            for (int j = 0; j < 8; ++j) {
                const int k = kc * 32 + q * 8 + j;
                float v;
                if (k < I_DIM)            v = W_ih[grow * I_DIM + k];
                else if (k == I_DIM)      v = b_ih[grow] + b_hh[grow];
                else if (k < 8 + HDIM)    v = W_hh[grow * HDIM + (k - 8)];
                else                      v = 0.0f;
                afrag[pt][kc][j] = (_Float16)(scl * v);
            }
        }
    }

    // ---- init both B buffers: bias col = 1, h = 0, pad = 0; buf0 x = x_0 ----
    for (int idx = tid; idx < 2 * BT * BSTRIDE; idx += 512) {
        const int buf = idx / (BT * BSTRIDE);
        const int rem = idx % (BT * BSTRIDE);
        const int n = rem / BSTRIDE, k = rem % BSTRIDE;
        float v = 0.0f;
        if (k == I_DIM)                 v = 1.0f;
        else if (k < I_DIM && buf == 0) v = x[(bbase + n) * (T_STEPS * I_DIM) + k];
        Blds[buf][n][k] = (_Float16)v;
    }
    __syncthreads();

    // cell ownership: units u0 = 8w+q (tile 2w), u1 = 8w+4+q (tile 2w+1)
    const int u0 = 8 * w + q;
    const int u1 = u0 + 4;

    // hoisted LDS pointers (loop-invariant)
    const _Float16* const rb0 = &Blds[0][n15][q * 8];
    const _Float16* const rb1 = &Blds[1][n15][q * 8];
    _Float16* const h0w0 = &Blds[0][n15][8 + u0];
    _Float16* const h1w0 = &Blds[0][n15][8 + u1];
    _Float16* const h0w1 = &Blds[1][n15][8 + u0];
    _Float16* const h1w1 = &Blds[1][n15][8 + u1];

    // x prefetch lanes: threads 0..127, (n = tid>>3, i = tid&7), i<7 active
    const int xn = tid >> 3, xi = tid & 7;
    const bool xact = (tid < 128) && (xi < I_DIM);
    const float* const xcol = x + (bbase + xn) * (T_STEPS * I_DIM) + xi;
    _Float16* const xw0 = &Blds[0][xn][xi];
    _Float16* const xw1 = &Blds[1][xn][xi];

    // 2-deep x pipeline
    float xA = xact ? xcol[1 * I_DIM] : 0.0f;   // x_1 (written during t=0)
    float xB = xact ? xcol[2 * I_DIM] : 0.0f;   // x_2 (written during t=1)

    float c0 = 0.0f, c1 = 0.0f, h0 = 0.0f, h1 = 0.0f;

#define LSTM_CELL(ACC, CREG, HREG)                                             \
    {                                                                          \
        const float A = FAST_EXP2(ACC[0]);                                     \
        const float F = FAST_EXP2(ACC[1]);                                     \
        const float E = FAST_EXP2(ACC[2]);                                     \
        const float O = FAST_EXP2(ACC[3]);                                     \
        const float ig = (E - 1.0f) * FAST_RCP((1.0f + A) * (E + 1.0f));       \
        const float fv = FAST_RCP(1.0f + F);                                   \
        CREG = fv * CREG + ig;                                                 \
        float cs = 2.88539008177792681472f * CREG;                             \
        cs = fminf(fmaxf(cs, -80.0f), 80.0f);                                  \
        const float C = FAST_EXP2(cs);                                         \
        HREG = (C - 1.0f) * FAST_RCP((1.0f + O) * (C + 1.0f));                 \
    }

#define LSTM_STEP(TT, RB, HW0, HW1, XW, XREG)                                  \
    {                                                                          \
        const half8 bf0 = *(const half8*)(RB);                                 \
        const half8 bf1 = *(const half8*)((RB) + 32);                          \
        const half8 bf2 = *(const half8*)((RB) + 64);                          \
        if (xact && ((TT) + 1 < T_STEPS)) *(XW) = (_Float16)XREG;              \
        {                                                                      \
            int tl = (TT) + 3;                                                 \
            if (tl >= T_STEPS) tl = T_STEPS - 1;                               \
            if (xact) XREG = xcol[tl * I_DIM];                                 \
        }                                                                      \
        f32x4 acc0 = {0.f, 0.f, 0.f, 0.f};                                     \
        f32x4 acc1 = {0.f, 0.f, 0.f, 0.f};                                     \
        acc0 = __builtin_amdgcn_mfma_f32_16x16x32_f16(afrag[0][0], bf0, acc0, 0, 0, 0); \
        acc1 = __builtin_amdgcn_mfma_f32_16x16x32_f16(afrag[1][0], bf0, acc1, 0, 0, 0); \
        acc0 = __builtin_amdgcn_mfma_f32_16x16x32_f16(afrag[0][1], bf1, acc0, 0, 0, 0); \
        acc1 = __builtin_amdgcn_mfma_f32_16x16x32_f16(afrag[1][1], bf1, acc1, 0, 0, 0); \
        acc0 = __builtin_amdgcn_mfma_f32_16x16x32_f16(afrag[0][2], bf2, acc0, 0, 0, 0); \
        acc1 = __builtin_amdgcn_mfma_f32_16x16x32_f16(afrag[1][2], bf2, acc1, 0, 0, 0); \
        LSTM_CELL(acc0, c0, h0)                                                \
        LSTM_CELL(acc1, c1, h1)                                                \
        *(HW0) = (_Float16)h0;                                                 \
        *(HW1) = (_Float16)h1;                                                 \
        __syncthreads();                                                       \
    }

    for (int t = 0; t < T_STEPS; t += 2) {
        // even step: read buf0, write buf1
        LSTM_STEP(t, rb0, h0w1, h1w1, xw1, xA)
        // odd step: read buf1, write buf0
        LSTM_STEP(t + 1, rb1, h0w0, h1w0, xw0, xB)
    }
#undef LSTM_STEP
#undef LSTM_CELL

    // ---- epilogue: out[b][j] = b_fc[j] + sum_u h[b][u] * W_fc[j][u] ----
    hlds[n15][u0] = h0;
    hlds[n15][u1] = h1;
    __syncthreads();
    if (tid < 256) {
        const int b = tid >> 4, j = tid & 15;
        float s = b_fc[j];
#pragma unroll 8
        for (int u = 0; u < HDIM; ++u)
            s += hlds[b][u] * W_fc[j * HDIM + u];
        out[(bbase + b) * 16 + j] = s;
    }
}

extern "C" void kernel_launch(void* const* d_in, const int* in_sizes, int n_in,
                              void* d_out, int out_size, void* d_ws, size_t ws_size,
                              hipStream_t stream) {
    const float* x    = (const float*)d_in[0];
    const float* W_ih = (const float*)d_in[1];
    const float* W_hh = (const float*)d_in[2];
    const float* b_ih = (const float*)d_in[3];
    const float* b_hh = (const float*)d_in[4];
    const float* W_fc = (const float*)d_in[5];
    const float* b_fc = (const float*)d_in[6];
    float* out = (float*)d_out;

    const int B = in_sizes[0] / (T_STEPS * I_DIM);  // 8192
    const int grid = B / BT;                         // 512 blocks

    lstm_mfma_kernel<<<grid, 512, 0, stream>>>(x, W_ih, W_hh, b_ih, b_hh,
                                               W_fc, b_fc, out);
}

// Round 7
// 198.205 us; speedup vs baseline: 11.7336x; 1.0153x over previous
//
#include <hip/hip_runtime.h>
#include <math.h>

#ifndef __has_builtin
#define __has_builtin(x) 0
#endif

#if __has_builtin(__builtin_amdgcn_rcpf)
#define FAST_RCP(x) __builtin_amdgcn_rcpf(x)
#else
#define FAST_RCP(x) (1.0f / (x))
#endif

#if __has_builtin(__builtin_amdgcn_exp2f)
#define FAST_EXP2(x) __builtin_amdgcn_exp2f(x)
#else
#define FAST_EXP2(x) exp2f(x)
#endif

typedef _Float16 half8 __attribute__((ext_vector_type(8)));
typedef _Float16 half2v __attribute__((ext_vector_type(2)));
typedef float f32x4 __attribute__((ext_vector_type(4)));
typedef float f32x2 __attribute__((ext_vector_type(2)));

constexpr int T_STEPS  = 180;
constexpr int I_DIM    = 7;
constexpr int HDIM     = 64;
constexpr int BT       = 16;    // batch tile per block
constexpr int BSTRIDE  = 104;   // halfs per B row: 208 B (96 data + 8 pad)

// Block = 512 threads = 8 waves; wave w owns row-tiles {2w, 2w+1}: one set of
// B-fragment reads (3 x b128) feeds 6 MFMAs and 2 cells/thread.
// Per step GEMM: gates[256 x 16] = W_aug[256 x 96(f16)] . v[96 x 16(f16)],
//   v = [x_t(7), 1, h_{t-1}(64), pad].
// A rows packed UNIT-MAJOR with ADJACENT-unit remap:
//   tile rt=2w+pt, row-quad rq, gate g  ->  param row g*64 + (8w + 2*rq + pt)
// so lane (q,n15)'s acc regs = i,f,g,o of unit 8w+2q+pt -> the thread's two
// cells are units {8w+2q, 8w+2q+1}: h stored as ONE packed b32 write.
// Activation scales pre-folded into weights (exp2-ready pre-activations).
// Cell math uses shared-denominator form: 5 exp2 + 2 rcp per cell.
// Branchless x pipeline (2-step-deep regs; xi==7 lanes write a dead pad col).
__global__ __launch_bounds__(512, 4) void lstm_mfma_kernel(
    const float* __restrict__ x,
    const float* __restrict__ W_ih,
    const float* __restrict__ W_hh,
    const float* __restrict__ b_ih,
    const float* __restrict__ b_hh,
    const float* __restrict__ W_fc,
    const float* __restrict__ b_fc,
    float* __restrict__ out) {
    __shared__ alignas(16) _Float16 Blds[2][BT][BSTRIDE];
    __shared__ alignas(16) float hlds[BT][HDIM + 4];   // fp32 h_T for epilogue

    const int tid  = (int)threadIdx.x;
    const int w    = tid >> 6;    // wave 0..7
    const int lane = tid & 63;
    const int q    = lane >> 4;   // quad 0..3
    const int n15  = lane & 15;   // batch col within tile
    const long bbase = (long)blockIdx.x * BT;

    // ---- A fragments, scale-folded, in registers for all 180 steps ----
    half8 afrag[2][3];
#pragma unroll
    for (int pt = 0; pt < 2; ++pt) {
        const int rq   = n15 >> 2;            // row-quad of this packed row
        const int gate = n15 & 3;
        const int unit = 8 * w + 2 * rq + pt; // adjacent-unit remap
        const int grow = gate * HDIM + unit;  // row in PyTorch [4H, *] params
        const float scl = (gate == 2) ? 2.88539008177792681472f
                                      : -1.44269504088896340736f;
#pragma unroll
        for (int kc = 0; kc < 3; ++kc) {
#pragma unroll
            for (int j = 0; j < 8; ++j) {
                const int k = kc * 32 + q * 8 + j;
                float v;
                if (k < I_DIM)            v = W_ih[grow * I_DIM + k];
                else if (k == I_DIM)      v = b_ih[grow] + b_hh[grow];
                else if (k < 8 + HDIM)    v = W_hh[grow * HDIM + (k - 8)];
                else                      v = 0.0f;
                afrag[pt][kc][j] = (_Float16)(scl * v);
            }
        }
    }

    // ---- init both B buffers: bias col = 1, h = 0, pad = 0; buf0 x = x_0 ----
    for (int idx = tid; idx < 2 * BT * BSTRIDE; idx += 512) {
        const int buf = idx / (BT * BSTRIDE);
        const int rem = idx % (BT * BSTRIDE);
        const int n = rem / BSTRIDE, k = rem % BSTRIDE;
        float v = 0.0f;
        if (k == I_DIM)                 v = 1.0f;
        else if (k < I_DIM && buf == 0) v = x[(bbase + n) * (T_STEPS * I_DIM) + k];
        Blds[buf][n][k] = (_Float16)v;
    }
    __syncthreads();

    // cell ownership: units u0 = 8w+2q, u0+1 (adjacent)
    const int u0 = 8 * w + 2 * q;

    // hoisted LDS pointers (loop-invariant)
    const _Float16* const rb0 = &Blds[0][n15][q * 8];
    const _Float16* const rb1 = &Blds[1][n15][q * 8];
    half2v* const hw0 = (half2v*)&Blds[0][n15][8 + u0];
    half2v* const hw1 = (half2v*)&Blds[1][n15][8 + u0];

    // x prefetch lanes: threads 0..127 (waves 0,1), n = tid>>3, i = tid&7.
    // Lane i==7 loads a valid dup column and stores to dead pad col 96+.
    const int xn = tid >> 3, xi7 = tid & 7;
    const int xi_ld = (xi7 < I_DIM) ? xi7 : I_DIM - 1;
    const int xi_st = (xi7 < I_DIM) ? xi7 : 96 + xn % 8;  // spread pad writes
    const bool xact = (tid < 128);                        // wave-uniform
    const float* const xcol = x + (bbase + xn) * (T_STEPS * I_DIM) + xi_ld;
    _Float16* const xw0 = &Blds[0][xn][xi_st];
    _Float16* const xw1 = &Blds[1][xn][xi_st];

    // 2-deep x pipeline
    float xA = xact ? xcol[1 * I_DIM] : 0.0f;   // x_1 (written during t=0)
    float xB = xact ? xcol[2 * I_DIM] : 0.0f;   // x_2 (written during t=1)

    float c0 = 0.0f, c1 = 0.0f, h0 = 0.0f, h1 = 0.0f;

    // cell: acc = {i',f',g',o'} exp2-ready.  A=2^i', F=2^f', E=2^g', O=2^o'
    //   c' = (c*P + (E-1)*Q) * rcp(P*Q),  P=(1+A)(E+1), Q=1+F
    //   h  = (C-1) * rcp((1+O)(C+1)),     C=2^(k*c') clamped
#define LSTM_CELL(ACC, CREG, HREG)                                             \
    {                                                                          \
        const float A = FAST_EXP2(ACC[0]);                                     \
        const float F = FAST_EXP2(ACC[1]);                                     \
        const float E = FAST_EXP2(ACC[2]);                                     \
        const float P = (1.0f + A) * (E + 1.0f);                               \
        const float Q = 1.0f + F;                                              \
        const float R = FAST_RCP(P * Q);                                       \
        CREG = (CREG * P + (E - 1.0f) * Q) * R;                                \
        const float O = FAST_EXP2(ACC[3]);                                     \
        float cs = 2.88539008177792681472f * CREG;                             \
        cs = fminf(fmaxf(cs, -80.0f), 80.0f);                                  \
        const float C = FAST_EXP2(cs);                                         \
        HREG = (C - 1.0f) * FAST_RCP((1.0f + O) * (C + 1.0f));                 \
    }

#define LSTM_STEP(TT, RB, HW, XW, XREG)                                        \
    {                                                                          \
        const half8 bf0 = *(const half8*)(RB);                                 \
        const half8 bf1 = *(const half8*)((RB) + 32);                          \
        const half8 bf2 = *(const half8*)((RB) + 64);                          \
        if (xact) {                                                            \
            *(XW) = (_Float16)XREG;                                            \
            int tl = (TT) + 3;                                                 \
            if (tl >= T_STEPS) tl = T_STEPS - 1;                               \
            XREG = xcol[tl * I_DIM];                                           \
        }                                                                      \
        f32x4 acc0 = {0.f, 0.f, 0.f, 0.f};                                     \
        f32x4 acc1 = {0.f, 0.f, 0.f, 0.f};                                     \
        acc0 = __builtin_amdgcn_mfma_f32_16x16x32_f16(afrag[0][0], bf0, acc0, 0, 0, 0); \
        acc1 = __builtin_amdgcn_mfma_f32_16x16x32_f16(afrag[1][0], bf0, acc1, 0, 0, 0); \
        acc0 = __builtin_amdgcn_mfma_f32_16x16x32_f16(afrag[0][1], bf1, acc0, 0, 0, 0); \
        acc1 = __builtin_amdgcn_mfma_f32_16x16x32_f16(afrag[1][1], bf1, acc1, 0, 0, 0); \
        acc0 = __builtin_amdgcn_mfma_f32_16x16x32_f16(afrag[0][2], bf2, acc0, 0, 0, 0); \
        acc1 = __builtin_amdgcn_mfma_f32_16x16x32_f16(afrag[1][2], bf2, acc1, 0, 0, 0); \
        LSTM_CELL(acc0, c0, h0)                                                \
        LSTM_CELL(acc1, c1, h1)                                                \
        *(HW) = (half2v){(_Float16)h0, (_Float16)h1};                          \
        __syncthreads();                                                       \
    }

    for (int t = 0; t < T_STEPS; t += 2) {
        LSTM_STEP(t, rb0, hw1, xw1, xA)       // read buf0, write buf1
        LSTM_STEP(t + 1, rb1, hw0, xw0, xB)   // read buf1, write buf0
    }
#undef LSTM_STEP
#undef LSTM_CELL

    // ---- epilogue: out[b][j] = b_fc[j] + sum_u h[b][u] * W_fc[j][u] ----
    *(f32x2*)&hlds[n15][u0] = (f32x2){h0, h1};
    __syncthreads();
    if (tid < 256) {
        const int b = tid >> 4, j = tid & 15;
        float s = b_fc[j];
#pragma unroll 8
        for (int u = 0; u < HDIM; ++u)
            s += hlds[b][u] * W_fc[j * HDIM + u];
        out[(bbase + b) * 16 + j] = s;
    }
}

extern "C" void kernel_launch(void* const* d_in, const int* in_sizes, int n_in,
                              void* d_out, int out_size, void* d_ws, size_t ws_size,
                              hipStream_t stream) {
    const float* x    = (const float*)d_in[0];
    const float* W_ih = (const float*)d_in[1];
    const float* W_hh = (const float*)d_in[2];
    const float* b_ih = (const float*)d_in[3];
    const float* b_hh = (const float*)d_in[4];
    const float* W_fc = (const float*)d_in[5];
    const float* b_fc = (const float*)d_in[6];
    float* out = (float*)d_out;

    const int B = in_sizes[0] / (T_STEPS * I_DIM);  // 8192
    const int grid = B / BT;                         // 512 blocks

    lstm_mfma_kernel<<<grid, 512, 0, stream>>>(x, W_ih, W_hh, b_ih, b_hh,
                                               W_fc, b_fc, out);
}